// Round 2
// baseline (258.409 us; speedup 1.0000x reference)
//
#include <hip/hip_runtime.h>
#include <math.h>

#define BS 32
#define OBJ 128
#define DD 256
#define RR 32
#define EE 64
#define NDEPTH 3

// ---------------------------------------------------------------------------
// Reduce A [32,128,4096] -> Ao [32,128,128], Ar [32,128,32], As [32,128].
// HBM-bound (67 MB read); one wave per (b,o) row, coalesced float4.
// ---------------------------------------------------------------------------
__global__ __launch_bounds__(256) void k_reduceA(const float* __restrict__ A,
                                                 float* __restrict__ Ao,
                                                 float* __restrict__ Ar,
                                                 float* __restrict__ As) {
    int wave = threadIdx.x >> 6;
    int lane = threadIdx.x & 63;
    int row  = blockIdx.x * 4 + wave;
    const float4* src = (const float4*)(A + (size_t)row * (RR * OBJ));
    float* AoRow = Ao + (size_t)row * OBJ;

    float4 arAcc = make_float4(0.f, 0.f, 0.f, 0.f);
#pragma unroll
    for (int it = 0; it < 16; ++it) {
        float4 v = src[it * 64 + lane];
        arAcc.x += v.x; arAcc.y += v.y; arAcc.z += v.z; arAcc.w += v.w;
        float s = v.x + v.y + v.z + v.w;
        s += __shfl_xor(s, 1);
        s += __shfl_xor(s, 2);
        s += __shfl_xor(s, 4);
        if ((lane & 7) == 0) AoRow[it * 8 + (lane >> 3)] = s;
    }
#pragma unroll
    for (int m = 8; m <= 32; m <<= 1) {
        arAcc.x += __shfl_xor(arAcc.x, m);
        arAcc.y += __shfl_xor(arAcc.y, m);
        arAcc.z += __shfl_xor(arAcc.z, m);
        arAcc.w += __shfl_xor(arAcc.w, m);
    }
    if (lane < 8) ((float4*)(Ar + (size_t)row * RR))[lane] = arAcc;
    float t = arAcc.x + arAcc.y + arAcc.z + arAcc.w;
    t += __shfl_xor(t, 1);
    t += __shfl_xor(t, 2);
    t += __shfl_xor(t, 4);
    if (lane == 0) As[row] = t;
}

// ---------------------------------------------------------------------------
// relpart[d][r][f] = sum_e rel_table[r,e] * W2[d][DD+e][f]
// ---------------------------------------------------------------------------
__global__ __launch_bounds__(256) void k_rel(const float* __restrict__ rel,
                                             const float* __restrict__ W2,
                                             float* __restrict__ relpart) {
    int dr = blockIdx.x;
    int d = dr >> 5, r = dr & 31;
    int f = threadIdx.x;
    const float* w  = W2 + (size_t)d * (DD + EE) * DD + (size_t)DD * DD;
    const float* rl = rel + (size_t)r * EE;
    float acc = 0.f;
#pragma unroll 8
    for (int e = 0; e < EE; ++e)
        acc = fmaf(rl[e], w[(size_t)e * DD + f], acc);
    relpart[(size_t)dr * DD + f] = acc;
}

// ---------------------------------------------------------------------------
// K1: C[4096 x 512] = X[4096 x 256] @ [W1[d] | W2a[d]].
// 64x128 tile / 256 threads / 4x8 microtile (cols tx*4 and 64+tx*4) / BK=32.
// Transposed X-tile in LDS (XT[k][m]) -> all operand reads are ds_read_b128.
// Double-buffered LDS, register prefetch, ONE barrier per K-step.
// grid (4, 64) = 256 blocks.
// ---------------------------------------------------------------------------
__global__ __launch_bounds__(256) void k_gemm1(const float* __restrict__ X,
                                               const float* __restrict__ W1,
                                               const float* __restrict__ W2,
                                               const float* __restrict__ b1,
                                               int d,
                                               float* __restrict__ h1,
                                               float* __restrict__ xw) {
    __shared__ float XT[2][32][68];    // [k][m], pad 68 keeps 16B align, 2-way banks
    __shared__ float Ws[2][32][132];   // [k][n], pad 132

    const int m0 = blockIdx.y * 64;
    const int n0blk = blockIdx.x * 128;            // 0,128 -> W1 ; 256,384 -> W2a
    const bool isW1 = (n0blk < 256);
    const int ncol0 = isW1 ? n0blk : (n0blk - 256);
    const float* Wbase = isW1 ? (W1 + (size_t)d * DD * DD)
                              : (W2 + (size_t)d * (DD + EE) * DD);

    const int tid = threadIdx.x;
    const int tx = tid & 15;           // n: cols tx*4 and 64+tx*4
    const int ty = tid >> 4;           // m: rows ty*4..ty*4+3

    // staging index precompute
    const int xm0 = tid >> 3;          // 0..31  (row for i=0); +32 for i=1
    const int xc  = tid & 7;           // k-chunk
    const int wr0 = tid >> 5;          // 0..7   (row for i); +8*i
    const int wc  = tid & 31;          // col chunk

    float4 xr[2], wr4[4];
    float acc0[4][4] = {};
    float acc1[4][4] = {};

    // prologue: load + stage k0 = 0
#pragma unroll
    for (int i = 0; i < 2; ++i)
        xr[i] = *(const float4*)(X + (size_t)(m0 + xm0 + 32 * i) * DD + xc * 4);
#pragma unroll
    for (int i = 0; i < 4; ++i)
        wr4[i] = *(const float4*)(Wbase + (size_t)(wr0 + 8 * i) * DD + ncol0 + wc * 4);
#pragma unroll
    for (int i = 0; i < 2; ++i) {
        XT[0][xc * 4 + 0][xm0 + 32 * i] = xr[i].x;
        XT[0][xc * 4 + 1][xm0 + 32 * i] = xr[i].y;
        XT[0][xc * 4 + 2][xm0 + 32 * i] = xr[i].z;
        XT[0][xc * 4 + 3][xm0 + 32 * i] = xr[i].w;
    }
#pragma unroll
    for (int i = 0; i < 4; ++i)
        *(float4*)(&Ws[0][wr0 + 8 * i][wc * 4]) = wr4[i];
    __syncthreads();

    for (int t = 0; t < 8; ++t) {
        const int cur = t & 1;
        if (t < 7) {                   // prefetch next tile into registers
            const int k0 = (t + 1) * 32;
#pragma unroll
            for (int i = 0; i < 2; ++i)
                xr[i] = *(const float4*)(X + (size_t)(m0 + xm0 + 32 * i) * DD + k0 + xc * 4);
#pragma unroll
            for (int i = 0; i < 4; ++i)
                wr4[i] = *(const float4*)(Wbase + (size_t)(k0 + wr0 + 8 * i) * DD + ncol0 + wc * 4);
        }
#pragma unroll
        for (int kk = 0; kk < 32; ++kk) {
            float4 a  = *(const float4*)(&XT[cur][kk][ty * 4]);
            float4 b0 = *(const float4*)(&Ws[cur][kk][tx * 4]);
            float4 b1v = *(const float4*)(&Ws[cur][kk][64 + tx * 4]);
            const float am[4] = {a.x, a.y, a.z, a.w};
#pragma unroll
            for (int i = 0; i < 4; ++i) {
                acc0[i][0] = fmaf(am[i], b0.x, acc0[i][0]);
                acc0[i][1] = fmaf(am[i], b0.y, acc0[i][1]);
                acc0[i][2] = fmaf(am[i], b0.z, acc0[i][2]);
                acc0[i][3] = fmaf(am[i], b0.w, acc0[i][3]);
                acc1[i][0] = fmaf(am[i], b1v.x, acc1[i][0]);
                acc1[i][1] = fmaf(am[i], b1v.y, acc1[i][1]);
                acc1[i][2] = fmaf(am[i], b1v.z, acc1[i][2]);
                acc1[i][3] = fmaf(am[i], b1v.w, acc1[i][3]);
            }
        }
        if (t < 7) {
            const int nxt = cur ^ 1;
#pragma unroll
            for (int i = 0; i < 2; ++i) {
                XT[nxt][xc * 4 + 0][xm0 + 32 * i] = xr[i].x;
                XT[nxt][xc * 4 + 1][xm0 + 32 * i] = xr[i].y;
                XT[nxt][xc * 4 + 2][xm0 + 32 * i] = xr[i].z;
                XT[nxt][xc * 4 + 3][xm0 + 32 * i] = xr[i].w;
            }
#pragma unroll
            for (int i = 0; i < 4; ++i)
                *(float4*)(&Ws[nxt][wr0 + 8 * i][wc * 4]) = wr4[i];
            __syncthreads();
        }
    }

    float4 bias0 = make_float4(0.f, 0.f, 0.f, 0.f);
    float4 bias1 = bias0;
    if (isW1) {
        bias0 = *(const float4*)(b1 + (size_t)d * DD + ncol0 + tx * 4);
        bias1 = *(const float4*)(b1 + (size_t)d * DD + ncol0 + 64 + tx * 4);
    }
    float* dst = isW1 ? h1 : xw;
#pragma unroll
    for (int i = 0; i < 4; ++i) {
        size_t base = (size_t)(m0 + ty * 4 + i) * DD + ncol0;
        float4 o0, o1;
        o0.x = acc0[i][0] + bias0.x; o0.y = acc0[i][1] + bias0.y;
        o0.z = acc0[i][2] + bias0.z; o0.w = acc0[i][3] + bias0.w;
        o1.x = acc1[i][0] + bias1.x; o1.y = acc1[i][1] + bias1.y;
        o1.z = acc1[i][2] + bias1.z; o1.w = acc1[i][3] + bias1.w;
        *(float4*)(dst + base + tx * 4) = o0;
        *(float4*)(dst + base + 64 + tx * 4) = o1;
    }
}

// ---------------------------------------------------------------------------
// K2 (per batch): agg = Ao[b] @ xw[b] + Ar[b] @ relpart[d]
// out = tanh(agg + As*b2 + h1 + x).  64x64 tile, 4x4 micro, BK=32, 5 K-steps,
// transposed A-tiles, double-buffered. grid (4, 2, 32) = 256 blocks.
// ---------------------------------------------------------------------------
__global__ __launch_bounds__(256) void k_agg(const float* __restrict__ Ao,
                                             const float* __restrict__ Ar,
                                             const float* __restrict__ As,
                                             const float* __restrict__ relpart,
                                             const float* __restrict__ b2,
                                             int d,
                                             const float* __restrict__ xw,
                                             const float* __restrict__ h1,
                                             const float* __restrict__ xin,
                                             float* __restrict__ xout) {
    __shared__ float AT[2][32][68];    // [k][m]
    __shared__ float Bs[2][32][68];    // [k][n]

    const int b  = blockIdx.z;
    const int m0 = blockIdx.y * 64;
    const int n0 = blockIdx.x * 64;
    const int tid = threadIdx.x;
    const int tx = tid & 15, ty = tid >> 4;

    const float* AoB = Ao + ((size_t)b * OBJ + m0) * OBJ;
    const float* ArB = Ar + ((size_t)b * OBJ + m0) * RR;
    const float* xwB = xw + (size_t)b * OBJ * DD;
    const float* rp  = relpart + (size_t)d * RR * DD;

    const int am0 = tid >> 3;          // 0..31 (+32)
    const int ac  = tid & 7;
    const int br0 = tid >> 4;          // 0..15 (+16)
    const int bc  = tid & 15;

    float4 areg[2], breg[2];
    float acc[4][4] = {};

    // prologue: stage step 0 (Ao k0=0, xw k0=0)
#pragma unroll
    for (int i = 0; i < 2; ++i) {
        areg[i] = *(const float4*)(AoB + (size_t)(am0 + 32 * i) * OBJ + ac * 4);
        breg[i] = *(const float4*)(xwB + (size_t)(br0 + 16 * i) * DD + n0 + bc * 4);
    }
#pragma unroll
    for (int i = 0; i < 2; ++i) {
        AT[0][ac * 4 + 0][am0 + 32 * i] = areg[i].x;
        AT[0][ac * 4 + 1][am0 + 32 * i] = areg[i].y;
        AT[0][ac * 4 + 2][am0 + 32 * i] = areg[i].z;
        AT[0][ac * 4 + 3][am0 + 32 * i] = areg[i].w;
        *(float4*)(&Bs[0][br0 + 16 * i][bc * 4]) = breg[i];
    }
    __syncthreads();

    for (int t = 0; t < 5; ++t) {
        const int cur = t & 1;
        if (t < 4) {                   // prefetch next
            if (t < 3) {
                const int k0 = (t + 1) * 32;
#pragma unroll
                for (int i = 0; i < 2; ++i) {
                    areg[i] = *(const float4*)(AoB + (size_t)(am0 + 32 * i) * OBJ + k0 + ac * 4);
                    breg[i] = *(const float4*)(xwB + (size_t)(k0 + br0 + 16 * i) * DD + n0 + bc * 4);
                }
            } else {                   // step 4 operands: Ar / relpart
#pragma unroll
                for (int i = 0; i < 2; ++i) {
                    areg[i] = *(const float4*)(ArB + (size_t)(am0 + 32 * i) * RR + ac * 4);
                    breg[i] = *(const float4*)(rp + (size_t)(br0 + 16 * i) * DD + n0 + bc * 4);
                }
            }
        }
#pragma unroll
        for (int kk = 0; kk < 32; ++kk) {
            float4 a = *(const float4*)(&AT[cur][kk][ty * 4]);
            float4 bv = *(const float4*)(&Bs[cur][kk][tx * 4]);
            const float am[4] = {a.x, a.y, a.z, a.w};
#pragma unroll
            for (int i = 0; i < 4; ++i) {
                acc[i][0] = fmaf(am[i], bv.x, acc[i][0]);
                acc[i][1] = fmaf(am[i], bv.y, acc[i][1]);
                acc[i][2] = fmaf(am[i], bv.z, acc[i][2]);
                acc[i][3] = fmaf(am[i], bv.w, acc[i][3]);
            }
        }
        if (t < 4) {
            const int nxt = cur ^ 1;
#pragma unroll
            for (int i = 0; i < 2; ++i) {
                AT[nxt][ac * 4 + 0][am0 + 32 * i] = areg[i].x;
                AT[nxt][ac * 4 + 1][am0 + 32 * i] = areg[i].y;
                AT[nxt][ac * 4 + 2][am0 + 32 * i] = areg[i].z;
                AT[nxt][ac * 4 + 3][am0 + 32 * i] = areg[i].w;
                *(float4*)(&Bs[nxt][br0 + 16 * i][bc * 4]) = breg[i];
            }
            __syncthreads();
        }
    }

    float4 b2v = *(const float4*)(b2 + (size_t)d * DD + n0 + tx * 4);
#pragma unroll
    for (int i = 0; i < 4; ++i) {
        int m = m0 + ty * 4 + i;
        float asv = As[(size_t)b * OBJ + m];
        size_t base = ((size_t)b * OBJ + m) * DD + n0 + tx * 4;
        float4 hv = *(const float4*)(h1 + base);
        float4 xv = *(const float4*)(xin + base);
        float4 o;
        o.x = tanhf(acc[i][0] + asv * b2v.x + hv.x + xv.x);
        o.y = tanhf(acc[i][1] + asv * b2v.y + hv.y + xv.y);
        o.z = tanhf(acc[i][2] + asv * b2v.z + hv.z + xv.z);
        o.w = tanhf(acc[i][3] + asv * b2v.w + hv.w + xv.w);
        *(float4*)(xout + base) = o;
    }
}

// ---------------------------------------------------------------------------
extern "C" void kernel_launch(void* const* d_in, const int* in_sizes, int n_in,
                              void* d_out, int out_size, void* d_ws, size_t ws_size,
                              hipStream_t stream) {
    const float* x    = (const float*)d_in[0];
    const float* A    = (const float*)d_in[1];
    const float* rel  = (const float*)d_in[2];
    const float* W1   = (const float*)d_in[3];
    const float* b1   = (const float*)d_in[4];
    const float* W2   = (const float*)d_in[5];
    const float* b2   = (const float*)d_in[6];
    float* out = (float*)d_out;

    float* Ao      = (float*)d_ws;                       // 32*128*128
    float* Ar      = Ao + (size_t)BS * OBJ * OBJ;        // 32*128*32
    float* As_     = Ar + (size_t)BS * OBJ * RR;         // 32*128
    float* relpart = As_ + (size_t)BS * OBJ;             // 3*32*256
    float* xwbuf   = relpart + (size_t)NDEPTH * RR * DD; // 32*128*256
    float* h1buf   = xwbuf + (size_t)BS * OBJ * DD;      // 32*128*256
    float* xbuf    = h1buf + (size_t)BS * OBJ * DD;      // 32*128*256

    k_reduceA<<<dim3(BS * OBJ / 4), dim3(256), 0, stream>>>(A, Ao, Ar, As_);
    k_rel<<<dim3(NDEPTH * RR), dim3(256), 0, stream>>>(rel, W2, relpart);

    const float* xcur = x;
    for (int d = 0; d < NDEPTH; ++d) {
        float* xnext = (d == NDEPTH - 1) ? out : xbuf;
        k_gemm1<<<dim3(4, 64), dim3(256), 0, stream>>>(xcur, W1, W2, b1, d, h1buf, xwbuf);
        k_agg<<<dim3(4, 2, BS), dim3(256), 0, stream>>>(Ao, Ar, As_, relpart, b2, d,
                                                        xwbuf, h1buf, xcur, xnext);
        xcur = xnext;
    }
}

// Round 4
// 237.644 us; speedup vs baseline: 1.0874x; 1.0874x over previous
//
#include <hip/hip_runtime.h>
#include <math.h>

#define BS 32
#define OBJ 128
#define DD 256
#define RR 32
#define EE 64
#define NDEPTH 3

// ---------------------------------------------------------------------------
// Reduce A [32,128,4096] -> Ao [32,128,128], Ar [32,128,32], As [32,128].
// HBM-bound (67 MB); one wave per (b,o) row, coalesced float4. (R1-proven)
// ---------------------------------------------------------------------------
__global__ __launch_bounds__(256) void k_reduceA(const float* __restrict__ A,
                                                 float* __restrict__ Ao,
                                                 float* __restrict__ Ar,
                                                 float* __restrict__ As) {
    int wave = threadIdx.x >> 6;
    int lane = threadIdx.x & 63;
    int row  = blockIdx.x * 4 + wave;
    const float4* src = (const float4*)(A + (size_t)row * (RR * OBJ));
    float* AoRow = Ao + (size_t)row * OBJ;

    float4 arAcc = make_float4(0.f, 0.f, 0.f, 0.f);
#pragma unroll
    for (int it = 0; it < 16; ++it) {
        float4 v = src[it * 64 + lane];
        arAcc.x += v.x; arAcc.y += v.y; arAcc.z += v.z; arAcc.w += v.w;
        float s = v.x + v.y + v.z + v.w;
        s += __shfl_xor(s, 1);
        s += __shfl_xor(s, 2);
        s += __shfl_xor(s, 4);
        if ((lane & 7) == 0) AoRow[it * 8 + (lane >> 3)] = s;
    }
#pragma unroll
    for (int m = 8; m <= 32; m <<= 1) {
        arAcc.x += __shfl_xor(arAcc.x, m);
        arAcc.y += __shfl_xor(arAcc.y, m);
        arAcc.z += __shfl_xor(arAcc.z, m);
        arAcc.w += __shfl_xor(arAcc.w, m);
    }
    if (lane < 8) ((float4*)(Ar + (size_t)row * RR))[lane] = arAcc;
    float t = arAcc.x + arAcc.y + arAcc.z + arAcc.w;
    t += __shfl_xor(t, 1);
    t += __shfl_xor(t, 2);
    t += __shfl_xor(t, 4);
    if (lane == 0) As[row] = t;
}

// ---------------------------------------------------------------------------
// relpart[d][r][f] = sum_e rel_table[r,e] * W2[d][DD+e][f]   (tiny)
// ---------------------------------------------------------------------------
__global__ __launch_bounds__(256) void k_rel(const float* __restrict__ rel,
                                             const float* __restrict__ W2,
                                             float* __restrict__ relpart) {
    int dr = blockIdx.x;
    int d = dr >> 5, r = dr & 31;
    int f = threadIdx.x;
    const float* w  = W2 + (size_t)d * (DD + EE) * DD + (size_t)DD * DD;
    const float* rl = rel + (size_t)r * EE;
    float acc = 0.f;
#pragma unroll 8
    for (int e = 0; e < EE; ++e)
        acc = fmaf(rl[e], w[(size_t)e * DD + f], acc);
    relpart[(size_t)dr * DD + f] = acc;
}

// ---------------------------------------------------------------------------
// K1: C[4096 x 512] = X[4096 x 256] @ [W1[d] | W2a[d]].
// 64x64 tile / 256 threads / 4x4 micro / BK=32 / grid (8,64)=512 blocks
// (2 blocks/CU, 8 waves/CU — the R1-proven occupancy).
// Transposed X-tile (XT[k][m]) so BOTH inner operand reads are ds_read_b128:
// 2 LDS insts per 16 FMA (24 cyc/kk/wave vs R1's 35.2).
// Double-buffered LDS, register prefetch, one barrier per K-step.
// ---------------------------------------------------------------------------
__global__ __launch_bounds__(256) void k_gemm1(const float* __restrict__ X,
                                               const float* __restrict__ W1,
                                               const float* __restrict__ W2,
                                               const float* __restrict__ b1,
                                               int d,
                                               float* __restrict__ h1,
                                               float* __restrict__ xw) {
    __shared__ float XT[2][32][68];    // [k][m], 68 -> 272B rows (16B aligned)
    __shared__ float Ws[2][32][68];    // [k][n]

    const int m0 = blockIdx.y * 64;
    const int n0blk = blockIdx.x * 64;             // 0..448
    const bool isW1 = (n0blk < 256);
    const int ncol0 = isW1 ? n0blk : (n0blk - 256);
    const float* Wbase = isW1 ? (W1 + (size_t)d * DD * DD)
                              : (W2 + (size_t)d * (DD + EE) * DD);

    const int tid = threadIdx.x;
    const int tx = tid & 15;           // n quad
    const int ty = tid >> 4;           // m quad

    // staging indices
    const int xm0 = tid >> 3;          // 0..31 (+32 for i=1)
    const int xc  = tid & 7;           // k chunk
    const int wr  = tid >> 4;          // 0..15 (+16 for i=1)
    const int wc  = tid & 15;          // n chunk
    const float* xrow = X + (size_t)(m0 + xm0) * DD + xc * 4;
    const float* wrow = Wbase + (size_t)wr * DD + ncol0 + wc * 4;

    float4 px[2], pw[2];
    float acc[4][4] = {};

    // prologue: tile 0 -> buf 0
#pragma unroll
    for (int i = 0; i < 2; ++i) {
        px[i] = *(const float4*)(xrow + (size_t)(32 * i) * DD);
        pw[i] = *(const float4*)(wrow + (size_t)(16 * i) * DD);
    }
#pragma unroll
    for (int i = 0; i < 2; ++i) {
        XT[0][xc * 4 + 0][xm0 + 32 * i] = px[i].x;
        XT[0][xc * 4 + 1][xm0 + 32 * i] = px[i].y;
        XT[0][xc * 4 + 2][xm0 + 32 * i] = px[i].z;
        XT[0][xc * 4 + 3][xm0 + 32 * i] = px[i].w;
        *(float4*)(&Ws[0][wr + 16 * i][wc * 4]) = pw[i];
    }
    __syncthreads();

    for (int t = 0; t < 8; ++t) {
        const int cur = t & 1;
        if (t < 7) {
            const int k0 = (t + 1) * 32;
#pragma unroll
            for (int i = 0; i < 2; ++i) {
                px[i] = *(const float4*)(xrow + (size_t)(32 * i) * DD + k0);
                pw[i] = *(const float4*)(wrow + (size_t)(k0 + 16 * i) * DD);
            }
        }
#pragma unroll
        for (int kk = 0; kk < 32; ++kk) {
            float4 a  = *(const float4*)(&XT[cur][kk][ty * 4]);
            float4 bv = *(const float4*)(&Ws[cur][kk][tx * 4]);
            const float am[4] = {a.x, a.y, a.z, a.w};
#pragma unroll
            for (int i = 0; i < 4; ++i) {
                acc[i][0] = fmaf(am[i], bv.x, acc[i][0]);
                acc[i][1] = fmaf(am[i], bv.y, acc[i][1]);
                acc[i][2] = fmaf(am[i], bv.z, acc[i][2]);
                acc[i][3] = fmaf(am[i], bv.w, acc[i][3]);
            }
        }
        if (t < 7) {
            const int nxt = cur ^ 1;
#pragma unroll
            for (int i = 0; i < 2; ++i) {
                XT[nxt][xc * 4 + 0][xm0 + 32 * i] = px[i].x;
                XT[nxt][xc * 4 + 1][xm0 + 32 * i] = px[i].y;
                XT[nxt][xc * 4 + 2][xm0 + 32 * i] = px[i].z;
                XT[nxt][xc * 4 + 3][xm0 + 32 * i] = px[i].w;
                *(float4*)(&Ws[nxt][wr + 16 * i][wc * 4]) = pw[i];
            }
            __syncthreads();
        }
    }

    float4 bias = make_float4(0.f, 0.f, 0.f, 0.f);
    if (isW1) bias = *(const float4*)(b1 + (size_t)d * DD + ncol0 + tx * 4);
    float* dst = isW1 ? h1 : xw;
#pragma unroll
    for (int i = 0; i < 4; ++i) {
        float4 o;
        o.x = acc[i][0] + bias.x;
        o.y = acc[i][1] + bias.y;
        o.z = acc[i][2] + bias.z;
        o.w = acc[i][3] + bias.w;
        *(float4*)(dst + (size_t)(m0 + ty * 4 + i) * DD + ncol0 + tx * 4) = o;
    }
}

// ---------------------------------------------------------------------------
// K2 (per batch): agg = Ao[b] @ xw[b] + Ar[b] @ relpart[d]
// out = tanh(agg + As*b2 + h1 + x).  64x64 tile, 4x4 micro, BK=32, 5 K-steps.
// Transposed A-tile (b128 inner reads); single-buffered 2-barrier (R1-proven
// at 4 waves/CU). In-place xin==xout is safe: xin read only at own indices.
// grid (4, 2, 32) = 256 blocks.
// ---------------------------------------------------------------------------
__global__ __launch_bounds__(256) void k_agg(const float* __restrict__ Ao,
                                             const float* __restrict__ Ar,
                                             const float* __restrict__ As,
                                             const float* __restrict__ relpart,
                                             const float* __restrict__ b2,
                                             int d,
                                             const float* __restrict__ xw,
                                             const float* __restrict__ h1,
                                             const float* __restrict__ xin,
                                             float* __restrict__ xout) {
    __shared__ float AT[32][68];       // [k][m]
    __shared__ float Bs[32][68];       // [k][n]

    const int b  = blockIdx.z;
    const int m0 = blockIdx.y * 64;
    const int n0 = blockIdx.x * 64;
    const int tid = threadIdx.x;
    const int tx = tid & 15, ty = tid >> 4;

    const float* AoB = Ao + ((size_t)b * OBJ + m0) * OBJ;
    const float* ArB = Ar + ((size_t)b * OBJ + m0) * RR;
    const float* xwB = xw + (size_t)b * OBJ * DD;
    const float* rp  = relpart + (size_t)d * RR * DD;

    const int am0 = tid >> 3;          // 0..31 (+32)
    const int ac  = tid & 7;
    const int br  = tid >> 4;          // 0..15 (+16)
    const int bc  = tid & 15;

    float acc[4][4] = {};

    for (int t = 0; t < 5; ++t) {
        float4 pa[2], pb[2];
        if (t < 4) {
            const int k0 = t * 32;
#pragma unroll
            for (int i = 0; i < 2; ++i) {
                pa[i] = *(const float4*)(AoB + (size_t)(am0 + 32 * i) * OBJ + k0 + ac * 4);
                pb[i] = *(const float4*)(xwB + (size_t)(k0 + br + 16 * i) * DD + n0 + bc * 4);
            }
        } else {
#pragma unroll
            for (int i = 0; i < 2; ++i) {
                pa[i] = *(const float4*)(ArB + (size_t)(am0 + 32 * i) * RR + ac * 4);
                pb[i] = *(const float4*)(rp + (size_t)(br + 16 * i) * DD + n0 + bc * 4);
            }
        }
        __syncthreads();               // previous iteration's reads done
#pragma unroll
        for (int i = 0; i < 2; ++i) {
            AT[ac * 4 + 0][am0 + 32 * i] = pa[i].x;
            AT[ac * 4 + 1][am0 + 32 * i] = pa[i].y;
            AT[ac * 4 + 2][am0 + 32 * i] = pa[i].z;
            AT[ac * 4 + 3][am0 + 32 * i] = pa[i].w;
            *(float4*)(&Bs[br + 16 * i][bc * 4]) = pb[i];
        }
        __syncthreads();
#pragma unroll
        for (int kk = 0; kk < 32; ++kk) {
            float4 a  = *(const float4*)(&AT[kk][ty * 4]);
            float4 bv = *(const float4*)(&Bs[kk][tx * 4]);
            const float am[4] = {a.x, a.y, a.z, a.w};
#pragma unroll
            for (int i = 0; i < 4; ++i) {
                acc[i][0] = fmaf(am[i], bv.x, acc[i][0]);
                acc[i][1] = fmaf(am[i], bv.y, acc[i][1]);
                acc[i][2] = fmaf(am[i], bv.z, acc[i][2]);
                acc[i][3] = fmaf(am[i], bv.w, acc[i][3]);
            }
        }
    }

    float4 b2v = *(const float4*)(b2 + (size_t)d * DD + n0 + tx * 4);
#pragma unroll
    for (int i = 0; i < 4; ++i) {
        int m = m0 + ty * 4 + i;
        float asv = As[(size_t)b * OBJ + m];
        size_t base = ((size_t)b * OBJ + m) * DD + n0 + tx * 4;
        float4 hv = *(const float4*)(h1 + base);
        float4 xv = *(const float4*)(xin + base);
        float4 o;
        o.x = tanhf(acc[i][0] + asv * b2v.x + hv.x + xv.x);
        o.y = tanhf(acc[i][1] + asv * b2v.y + hv.y + xv.y);
        o.z = tanhf(acc[i][2] + asv * b2v.z + hv.z + xv.z);
        o.w = tanhf(acc[i][3] + asv * b2v.w + hv.w + xv.w);
        *(float4*)(xout + base) = o;
    }
}

// ---------------------------------------------------------------------------
extern "C" void kernel_launch(void* const* d_in, const int* in_sizes, int n_in,
                              void* d_out, int out_size, void* d_ws, size_t ws_size,
                              hipStream_t stream) {
    const float* x    = (const float*)d_in[0];
    const float* A    = (const float*)d_in[1];
    const float* rel  = (const float*)d_in[2];
    const float* W1   = (const float*)d_in[3];
    const float* b1   = (const float*)d_in[4];
    const float* W2   = (const float*)d_in[5];
    const float* b2   = (const float*)d_in[6];
    float* out = (float*)d_out;

    float* Ao      = (float*)d_ws;                       // 32*128*128
    float* Ar      = Ao + (size_t)BS * OBJ * OBJ;        // 32*128*32
    float* As_     = Ar + (size_t)BS * OBJ * RR;         // 32*128
    float* relpart = As_ + (size_t)BS * OBJ;             // 3*32*256
    float* xwbuf   = relpart + (size_t)NDEPTH * RR * DD; // 32*128*256
    float* h1buf   = xwbuf + (size_t)BS * OBJ * DD;      // 32*128*256
    float* xbuf    = h1buf + (size_t)BS * OBJ * DD;      // 32*128*256

    k_reduceA<<<dim3(BS * OBJ / 4), dim3(256), 0, stream>>>(A, Ao, Ar, As_);
    k_rel<<<dim3(NDEPTH * RR), dim3(256), 0, stream>>>(rel, W2, relpart);

    const float* xcur = x;
    for (int d = 0; d < NDEPTH; ++d) {
        float* xnext = (d == NDEPTH - 1) ? out : xbuf;
        k_gemm1<<<dim3(8, 64), dim3(256), 0, stream>>>(xcur, W1, W2, b1, d, h1buf, xwbuf);
        k_agg<<<dim3(4, 2, BS), dim3(256), 0, stream>>>(Ao, Ar, As_, relpart, b2, d,
                                                        xwbuf, h1buf, xcur, xnext);
        xcur = xnext;
    }
}